// Round 2
// baseline (118.656 us; speedup 1.0000x reference)
//
#include <hip/hip_runtime.h>
#include <math.h>

// Depthwise 5x5 Gaussian blur, sigma from device scalar.
// x: (16, 256, 64, 64) fp32, out same, zero pad 2. Separable.
// One block per (n,c) plane. Single LDS buffer (padded input plane),
// ONE barrier; horizontal+vertical passes fused in registers.

constexpr int Hh   = 64;
constexpr int Ww   = 64;
constexpr int KS   = 5;
constexpr int PADc = 2;
constexpr int TH   = Hh + 2 * PADc;  // 68 padded rows
constexpr int IN_STR = 72;           // 288 B row stride -> float4-aligned rows

__global__ __launch_bounds__(256, 6) void gauss5(const float* __restrict__ x,
                                                 const float* __restrict__ sigma,
                                                 float* __restrict__ out) {
    __shared__ float sIn[TH * IN_STR];  // 19,584 B

    const int t = threadIdx.x;
    const size_t plane = blockIdx.x;  // n*C + c
    const float* __restrict__ xp = x + plane * (size_t)(Hh * Ww);
    float* __restrict__ op = out + plane * (size_t)(Hh * Ww);

    // --- normalized 1-D Gaussian taps (outer product sums to 1, matching ref) ---
    const float sg = sigma[0];
    const float c2 = -1.0f / (2.0f * sg * sg);
    float g[KS];
    float gsum = 0.0f;
#pragma unroll
    for (int i = 0; i < KS; ++i) {
        float d = (float)(i - PADc);
        g[i] = expf(d * d * c2);
        gsum += g[i];
    }
    const float ginv = 1.0f / gsum;
#pragma unroll
    for (int i = 0; i < KS; ++i) g[i] *= ginv;

    // --- zero ONLY the halo (disjoint from interior stores -> no barrier
    //     needed between this and the staging loop) ---
    // rows 0,1,66,67: cols 0..67  (4*68 = 272 words)
    // rows 2..65:     cols {0,1,66,67}  (64*4 = 256 words)  -> 528 total
    for (int i = t; i < 528; i += 256) {
        if (i < 272) {
            int rr  = i / 68;
            int cc  = i - rr * 68;
            int row = (rr < 2) ? rr : (rr + 64);
            sIn[row * IN_STR + cc] = 0.0f;
        } else {
            int j   = i - 272;
            int row = 2 + (j >> 2);
            int k   = j & 3;
            int col = (k < 2) ? k : (k + 64);
            sIn[row * IN_STR + col] = 0.0f;
        }
    }

    // --- stage 64x64 interior (float4 coalesced global reads) ---
    const float4* __restrict__ x4 = (const float4*)xp;
#pragma unroll
    for (int k = 0; k < 4; ++k) {
        int idx = t + k * 256;        // float4 index 0..1023
        int r   = idx >> 4;           // 16 float4 per row
        int c   = (idx & 15) << 2;
        float4 v = x4[idx];
        float* dst = &sIn[(r + PADc) * IN_STR + c + PADc];
        dst[0] = v.x; dst[1] = v.y; dst[2] = v.z; dst[3] = v.w;
    }
    __syncthreads();  // the ONLY barrier

    // --- fused separable conv in registers ---
    // thread -> output quad-col c4 (0..15), output rows r0..r0+3.
    // Needs horizontal conv of padded rows r0..r0+7 over padded cols
    // [4*c4, 4*c4+8): two aligned float4 LDS reads per row.
    const int c4 = t & 15;
    const int r0 = (t >> 4) << 2;

    float4 h[8];
#pragma unroll
    for (int i = 0; i < 8; ++i) {
        const float* src = &sIn[(r0 + i) * IN_STR + (c4 << 2)];
        float4 a = *(const float4*)(src);
        float4 b = *(const float4*)(src + 4);
        h[i].x = g[0]*a.x + g[1]*a.y + g[2]*a.z + g[3]*a.w + g[4]*b.x;
        h[i].y = g[0]*a.y + g[1]*a.z + g[2]*a.w + g[3]*b.x + g[4]*b.y;
        h[i].z = g[0]*a.z + g[1]*a.w + g[2]*b.x + g[3]*b.y + g[4]*b.z;
        h[i].w = g[0]*a.w + g[1]*b.x + g[2]*b.y + g[3]*b.z + g[4]*b.w;
    }

    float4* __restrict__ o4 = (float4*)op;
#pragma unroll
    for (int i = 0; i < 4; ++i) {
        float4 acc;
        acc.x = g[0]*h[i].x; acc.y = g[0]*h[i].y;
        acc.z = g[0]*h[i].z; acc.w = g[0]*h[i].w;
#pragma unroll
        for (int j = 1; j < KS; ++j) {
            acc.x += g[j] * h[i+j].x;
            acc.y += g[j] * h[i+j].y;
            acc.z += g[j] * h[i+j].z;
            acc.w += g[j] * h[i+j].w;
        }
        o4[(r0 + i) * 16 + c4] = acc;
    }
}

extern "C" void kernel_launch(void* const* d_in, const int* in_sizes, int n_in,
                              void* d_out, int out_size, void* d_ws, size_t ws_size,
                              hipStream_t stream) {
    const float* x     = (const float*)d_in[0];
    const float* sigma = (const float*)d_in[1];
    float* out         = (float*)d_out;
    const int planes = in_sizes[0] / (Hh * Ww);  // 16*256 = 4096
    gauss5<<<planes, 256, 0, stream>>>(x, sigma, out);
}

// Round 3
// 112.240 us; speedup vs baseline: 1.0572x; 1.0572x over previous
//
#include <hip/hip_runtime.h>
#include <math.h>

// Depthwise 5x5 Gaussian blur, sigma from device scalar.
// x: (16, 256, 64, 64) fp32, out same, zero pad 2. Separable.
// 4 planes per block, double-buffered LDS, prefetch next plane's
// global loads before computing the current one -> memory pipe
// stays busy instead of the load/compute phase structure of R1/R2.

constexpr int Hh   = 64;
constexpr int Ww   = 64;
constexpr int KS   = 5;
constexpr int PADc = 2;
constexpr int TH   = Hh + 2 * PADc;   // 68 padded rows
constexpr int IN_STR = 72;            // 288 B row stride -> float4-aligned rows
constexpr int PPB  = 4;               // planes per block

__global__ __launch_bounds__(256, 4) void gauss5(const float* __restrict__ x,
                                                 const float* __restrict__ sigma,
                                                 float* __restrict__ out) {
    __shared__ alignas(16) float sIn[2][TH * IN_STR];  // 2 x 19,584 B

    const int t = threadIdx.x;
    const size_t plane0 = (size_t)blockIdx.x * PPB;

    // --- normalized 1-D Gaussian taps (outer product sums to 1, matching ref) ---
    const float sg = sigma[0];
    const float c2 = -1.0f / (2.0f * sg * sg);
    float g[KS];
    float gsum = 0.0f;
#pragma unroll
    for (int i = 0; i < KS; ++i) {
        float d = (float)(i - PADc);
        g[i] = expf(d * d * c2);
        gsum += g[i];
    }
    const float ginv = 1.0f / gsum;
#pragma unroll
    for (int i = 0; i < KS; ++i) g[i] *= ginv;

    // --- zero the halos of BOTH buffers once (interior stores never touch
    //     halo words, so halos stay zero across all planes) ---
    for (int i = t; i < 528; i += 256) {
        int row, col;
        if (i < 272) {
            int rr = i / 68;
            col = i - rr * 68;
            row = (rr < 2) ? rr : (rr + 64);
        } else {
            int j = i - 272;
            row = 2 + (j >> 2);
            int k = j & 3;
            col = (k < 2) ? k : (k + 64);
        }
        sIn[0][row * IN_STR + col] = 0.0f;
        sIn[1][row * IN_STR + col] = 0.0f;
    }

    const int c4 = t & 15;            // quad-col 0..15
    const int r0 = (t >> 4) << 2;     // output rows r0..r0+3

    // --- prologue: load plane0 into buffer 0 ---
    float4 v[4];
    {
        const float4* __restrict__ x4 = (const float4*)(x + plane0 * (Hh * Ww));
#pragma unroll
        for (int k = 0; k < 4; ++k) v[k] = x4[t + k * 256];
#pragma unroll
        for (int k = 0; k < 4; ++k) {
            int idx = t + k * 256;
            int r   = idx >> 4;
            int c   = (idx & 15) << 2;
            float* dst = &sIn[0][(r + PADc) * IN_STR + c + PADc];
            dst[0] = v[k].x; dst[1] = v[k].y; dst[2] = v[k].z; dst[3] = v[k].w;
        }
    }
    __syncthreads();

    for (int p = 0; p < PPB; ++p) {
        // --- prefetch next plane's global loads (overlaps compute below) ---
        if (p + 1 < PPB) {
            const float4* __restrict__ xn =
                (const float4*)(x + (plane0 + p + 1) * (Hh * Ww));
#pragma unroll
            for (int k = 0; k < 4; ++k) v[k] = xn[t + k * 256];
        }

        // --- fused separable conv from buffer p&1 ---
        const float* __restrict__ buf = sIn[p & 1];
        float4 h[8];
#pragma unroll
        for (int i = 0; i < 8; ++i) {
            const float* src = &buf[(r0 + i) * IN_STR + (c4 << 2)];
            float4 a = *(const float4*)(src);
            float4 b = *(const float4*)(src + 4);
            h[i].x = g[0]*a.x + g[1]*a.y + g[2]*a.z + g[3]*a.w + g[4]*b.x;
            h[i].y = g[0]*a.y + g[1]*a.z + g[2]*a.w + g[3]*b.x + g[4]*b.y;
            h[i].z = g[0]*a.z + g[1]*a.w + g[2]*b.x + g[3]*b.y + g[4]*b.z;
            h[i].w = g[0]*a.w + g[1]*b.x + g[2]*b.y + g[3]*b.z + g[4]*b.w;
        }

        float4* __restrict__ o4 = (float4*)(out + (plane0 + p) * (Hh * Ww));
#pragma unroll
        for (int i = 0; i < 4; ++i) {
            float4 acc;
            acc.x = g[0]*h[i].x; acc.y = g[0]*h[i].y;
            acc.z = g[0]*h[i].z; acc.w = g[0]*h[i].w;
#pragma unroll
            for (int j = 1; j < KS; ++j) {
                acc.x += g[j] * h[i+j].x;
                acc.y += g[j] * h[i+j].y;
                acc.z += g[j] * h[i+j].z;
                acc.w += g[j] * h[i+j].w;
            }
            o4[(r0 + i) * 16 + c4] = acc;
        }

        // --- stage prefetched plane into the other buffer ---
        // Safe without a pre-write barrier: buffer (p+1)&1 was last READ in
        // iteration p-1, and the barrier at the end of iteration p-1 ordered
        // those reads before any iteration-p writes.
        if (p + 1 < PPB) {
            float* __restrict__ nbuf = sIn[(p + 1) & 1];
#pragma unroll
            for (int k = 0; k < 4; ++k) {
                int idx = t + k * 256;
                int r   = idx >> 4;
                int c   = (idx & 15) << 2;
                float* dst = &nbuf[(r + PADc) * IN_STR + c + PADc];
                dst[0] = v[k].x; dst[1] = v[k].y; dst[2] = v[k].z; dst[3] = v[k].w;
            }
            __syncthreads();
        }
    }
}

extern "C" void kernel_launch(void* const* d_in, const int* in_sizes, int n_in,
                              void* d_out, int out_size, void* d_ws, size_t ws_size,
                              hipStream_t stream) {
    const float* x     = (const float*)d_in[0];
    const float* sigma = (const float*)d_in[1];
    float* out         = (float*)d_out;
    const int planes = in_sizes[0] / (Hh * Ww);  // 4096
    gauss5<<<planes / PPB, 256, 0, stream>>>(x, sigma, out);
}